// Round 9
// baseline (379.888 us; speedup 1.0000x reference)
//
#include <hip/hip_runtime.h>

#define NG 48
#define NT 6                   // 4 A tiles per axis (8 cells)
#define NTILES (NT * NT * NT)  // 216
#define CAP 1536               // max atoms per (type,tile); expected max ~1010
#define NSEG 8
// ws layout:
//   [0,      2592)  int cnt[3*216]
//   [2592,   5184)  int done[3*216]
//   [8192,  ~2.0M)  u16 lists[3*216][CAP]
//   [2MiB,  ~12.6M) float copies[3*216][NSEG][512]
#define DONE_OFF   2592
#define LISTS_OFF  8192
#define COPIES_OFF (2u << 20)

__device__ __forceinline__ float type_r(int type) {
    return (type == 0) ? 1.7f : ((type == 1) ? 1.55f : 1.52f);
}

// Phase 1 (two-level histogram, proven in R7): per-256-atom-block LDS counts,
// ONE global atomicAdd per (block, active tile) to reserve a range, then
// plain stores of atom indices into the reserved slots.
__global__ __launch_bounds__(256) void bin_kernel(
    const float* __restrict__ vC, const float* __restrict__ vN,
    const float* __restrict__ vO, int* __restrict__ cnt,
    unsigned short* __restrict__ lists, int natoms)
{
    const int type = blockIdx.y;
    const float r = type_r(type);
    const float b = 1.5f * r + 1e-3f;
    const float* __restrict__ vecs = (type == 0) ? vC : ((type == 1) ? vN : vO);
    const int tid  = threadIdx.x;
    const int atom = blockIdx.x * 256 + tid;

    __shared__ int lcnt[NTILES];
    __shared__ int lbase[NTILES];
    __shared__ int lfill[NTILES];
    if (tid < NTILES) { lcnt[tid] = 0; lfill[tid] = 0; }
    __syncthreads();

    int x0 = 1, x1 = 0, y0 = 1, y1 = 0, z0 = 1, z1 = 0;
    if (atom < natoms) {
        const float vx = vecs[3 * atom + 0] + 23.5f;  // vec = raw + 24 - 0.5
        const float vy = vecs[3 * atom + 1] + 23.5f;
        const float vz = vecs[3 * atom + 2] + 23.5f;
        // tile t intersects the 1.5r halo iff 4t > v - b - 3.5 and 4t < v + b
        x0 = max(0,      (int)floorf((vx - 3.5f - b) * 0.25f) + 1);
        x1 = min(NT - 1, (int)ceilf ((vx + b)        * 0.25f) - 1);
        y0 = max(0,      (int)floorf((vy - 3.5f - b) * 0.25f) + 1);
        y1 = min(NT - 1, (int)ceilf ((vy + b)        * 0.25f) - 1);
        z0 = max(0,      (int)floorf((vz - 3.5f - b) * 0.25f) + 1);
        z1 = min(NT - 1, (int)ceilf ((vz + b)        * 0.25f) - 1);
    }
    const bool has = (x0 <= x1) & (y0 <= y1) & (z0 <= z1);

    if (has)
        for (int tx = x0; tx <= x1; ++tx)
            for (int ty = y0; ty <= y1; ++ty)
                for (int tz = z0; tz <= z1; ++tz)
                    atomicAdd(&lcnt[(tx * NT + ty) * NT + tz], 1);   // LDS
    __syncthreads();

    if (tid < NTILES && lcnt[tid] > 0)
        lbase[tid] = atomicAdd(&cnt[type * NTILES + tid], lcnt[tid]);
    __syncthreads();

    if (has)
        for (int tx = x0; tx <= x1; ++tx)
            for (int ty = y0; ty <= y1; ++ty)
                for (int tz = z0; tz <= z1; ++tz) {
                    const int tl = (tx * NT + ty) * NT + tz;
                    const int p  = lbase[tl] + atomicAdd(&lfill[tl], 1);  // LDS
                    if (p < CAP)
                        lists[(size_t)(type * NTILES + tl) * CAP + p] =
                            (unsigned short)atom;
                }
}

// Phase 2+3 fused: one block per (segment, tile, type). Active blocks store
// 512 partials (2KB, coalesced) into compact copies[lt][s]. The LAST of the
// tile's NSEG blocks (device-scope fence + done-counter election) sums the
// non-empty segments in fixed order and writes the tile's output cells —
// zeros for inactive tiles. Output: exactly-once, deterministic sum order.
__global__ __launch_bounds__(256) void gather_fold(
    const float* __restrict__ vC, const float* __restrict__ vN,
    const float* __restrict__ vO, const int* __restrict__ cnt,
    int* __restrict__ done, const unsigned short* __restrict__ lists,
    float* __restrict__ copies, float* __restrict__ out)
{
    const int type = blockIdx.y;
    const float r = type_r(type);
    const float* __restrict__ vecs = (type == 0) ? vC : ((type == 1) ? vN : vO);

    // segment-major: consecutive blocks -> different tiles (XCD spread)
    const int s = blockIdx.x / NTILES;
    const int t = blockIdx.x - s * NTILES;
    const int tx = t / (NT * NT);
    const int ty = (t / NT) % NT;
    const int tz = t % NT;

    const int tid = threadIdx.x;
    const int lx  = tid >> 6;          // 0..3
    const int ly  = (tid >> 3) & 7;
    const int lz  = tid & 7;

    const float b      = 1.5f * r;
    const float r15sq  = b * b;
    const float rr     = r * r;
    const float E2     = 7.3890562f;
    const float c2a    = 4.0f / (E2 * rr);
    const float c2b    = 12.0f / (E2 * r);
    const float c2c    = 9.0f / E2;
    const float n2orr  = -2.0f / rr;

    const float px0 = 0.5f * (float)(tx * 8 + lx);
    const float px1 = px0 + 2.0f;
    const float py  = 0.5f * (float)(ty * 8 + ly);
    const float pz  = 0.5f * (float)(tz * 8 + lz);

    __shared__ float4 sa[256];

    const int lt  = type * NTILES + t;
    const int n   = min(cnt[lt], CAP);
    const int len = (n + NSEG - 1) / NSEG;          // 0 when n==0
    const int start = s * len;
    const int end   = min(n, start + len);
    const unsigned short* __restrict__ lst = lists + (size_t)lt * CAP;
    float* __restrict__ cp = copies + ((size_t)lt * NSEG) * 512;

    float acc0 = 0.0f, acc1 = 0.0f;

    for (int base = start; base < end; base += 256) {
        const int m = min(256, end - base);
        if (tid < m) {
            const int idx = (int)lst[base + tid];
            sa[tid] = make_float4(vecs[3 * idx + 0] + 23.5f,
                                  vecs[3 * idx + 1] + 23.5f,
                                  vecs[3 * idx + 2] + 23.5f, 0.0f);
        }
        __syncthreads();

        for (int j = 0; j < m; ++j) {
            const float4 a = sa[j];               // one b128 LDS broadcast
            const float dy  = a.y - py;
            const float dz  = a.z - pz;
            const float syz = fmaf(dy, dy, dz * dz);
            const float dx0 = a.x - px0;
            const float d2a = fmaf(dx0, dx0, syz);
            const float dx1 = a.x - px1;
            const float d2b = fmaf(dx1, dx1, syz);
            const bool h0 = d2a < r15sq;
            const bool h1 = d2b < r15sq;
            if (__ballot(h0 | h1) == 0ull) continue;   // whole-wave miss cull
            if (h0) {
                const float d = sqrtf(d2a);
                acc0 += (d < r) ? __expf(n2orr * d2a)
                                : fmaf(c2a, d2a, fmaf(-c2b, d, c2c));
            }
            if (h1) {
                const float d = sqrtf(d2b);
                acc1 += (d < r) ? __expf(n2orr * d2b)
                                : fmaf(c2a, d2b, fmaf(-c2b, d, c2c));
            }
        }
        __syncthreads();
    }

    if (start < end) {                    // this segment evaluated something
        cp[(size_t)s * 512 + tid]       = acc0;
        cp[(size_t)s * 512 + 256 + tid] = acc1;
    }

    // ---- last-block election & fold ----
    __threadfence();                      // release partials to device scope
    __shared__ int prev;
    if (tid == 0) prev = atomicAdd(&done[lt], 1);
    __syncthreads();
    if (prev != NSEG - 1) return;

    __threadfence();                      // acquire: see other blocks' stores

    float o0 = 0.0f, o1 = 0.0f;
    for (int ss = 0; ss < NSEG; ++ss) {
        if (ss * len >= n) break;         // segment never stored
        o0 += cp[(size_t)ss * 512 + tid];
        o1 += cp[(size_t)ss * 512 + 256 + tid];
    }

    const int X0 = tx * 8 + lx;
    const int Y  = ty * 8 + ly;
    const int Z  = tz * 8 + lz;
    float* __restrict__ o = out + (size_t)type * NG * NG * NG;
    o[((X0      * NG) + Y) * NG + Z] = o0;
    o[(((X0 + 4) * NG) + Y) * NG + Z] = o1;
}

extern "C" void kernel_launch(void* const* d_in, const int* in_sizes, int n_in,
                              void* d_out, int out_size, void* d_ws, size_t ws_size,
                              hipStream_t stream) {
    const float* vC = (const float*)d_in[0];
    const float* vN = (const float*)d_in[1];
    const float* vO = (const float*)d_in[2];
    float* out = (float*)d_out;

    int* cnt  = (int*)d_ws;
    int* done = (int*)((char*)d_ws + DONE_OFF);
    unsigned short* lists = (unsigned short*)((char*)d_ws + LISTS_OFF);
    float* copies = (float*)((char*)d_ws + COPIES_OFF);

    const int natoms = in_sizes[0] / 3;   // 16384

    hipMemsetAsync(d_ws, 0, 8192, stream);   // cnt + done

    dim3 bgrid((natoms + 255) / 256, 3, 1);
    bin_kernel<<<bgrid, 256, 0, stream>>>(vC, vN, vO, cnt, lists, natoms);

    dim3 ggrid(NTILES * NSEG, 3, 1);
    gather_fold<<<ggrid, 256, 0, stream>>>(vC, vN, vO, cnt, done, lists,
                                           copies, out);
}

// Round 10
// 44.468 us; speedup vs baseline: 8.5429x; 8.5429x over previous
//
#include <hip/hip_runtime.h>

#define NG 48
#define NT 6                   // 4 A tiles per axis (8 cells)
#define NTILES (NT * NT * NT)  // 216
#define CAP 1536               // max atoms per (type,tile); expected max ~1010
#define MAXSEG 8
// ws layout:
//   [0,     2592)   int cnt[3*216]
//   [8192, ~2.0M)   u16 lists[3*216][CAP]
//   [2MiB, +10.6M)  float copies[3*216][MAXSEG][512]   (compact per-tile)
#define LISTS_OFF  8192
#define COPIES_OFF (2u << 20)

__device__ __forceinline__ float type_r(int type) {
    return (type == 0) ? 1.7f : ((type == 1) ? 1.55f : 1.52f);
}

// Phase 1 (two-level histogram, proven in R7): per-256-atom-block LDS counts,
// ONE global atomicAdd per (block, active tile) to reserve a range, then
// plain stores of atom indices into the reserved slots.
__global__ __launch_bounds__(256) void bin_kernel(
    const float* __restrict__ vC, const float* __restrict__ vN,
    const float* __restrict__ vO, int* __restrict__ cnt,
    unsigned short* __restrict__ lists, int natoms)
{
    const int type = blockIdx.y;
    const float r = type_r(type);
    const float b = 1.5f * r + 1e-3f;
    const float* __restrict__ vecs = (type == 0) ? vC : ((type == 1) ? vN : vO);
    const int tid  = threadIdx.x;
    const int atom = blockIdx.x * 256 + tid;

    __shared__ int lcnt[NTILES];
    __shared__ int lbase[NTILES];
    __shared__ int lfill[NTILES];
    if (tid < NTILES) { lcnt[tid] = 0; lfill[tid] = 0; }
    __syncthreads();

    int x0 = 1, x1 = 0, y0 = 1, y1 = 0, z0 = 1, z1 = 0;
    if (atom < natoms) {
        const float vx = vecs[3 * atom + 0] + 23.5f;  // vec = raw + 24 - 0.5
        const float vy = vecs[3 * atom + 1] + 23.5f;
        const float vz = vecs[3 * atom + 2] + 23.5f;
        // tile t intersects the 1.5r halo iff 4t > v - b - 3.5 and 4t < v + b
        x0 = max(0,      (int)floorf((vx - 3.5f - b) * 0.25f) + 1);
        x1 = min(NT - 1, (int)ceilf ((vx + b)        * 0.25f) - 1);
        y0 = max(0,      (int)floorf((vy - 3.5f - b) * 0.25f) + 1);
        y1 = min(NT - 1, (int)ceilf ((vy + b)        * 0.25f) - 1);
        z0 = max(0,      (int)floorf((vz - 3.5f - b) * 0.25f) + 1);
        z1 = min(NT - 1, (int)ceilf ((vz + b)        * 0.25f) - 1);
    }
    const bool has = (x0 <= x1) & (y0 <= y1) & (z0 <= z1);

    if (has)
        for (int tx = x0; tx <= x1; ++tx)
            for (int ty = y0; ty <= y1; ++ty)
                for (int tz = z0; tz <= z1; ++tz)
                    atomicAdd(&lcnt[(tx * NT + ty) * NT + tz], 1);   // LDS
    __syncthreads();

    if (tid < NTILES && lcnt[tid] > 0)
        lbase[tid] = atomicAdd(&cnt[type * NTILES + tid], lcnt[tid]);
    __syncthreads();

    if (has)
        for (int tx = x0; tx <= x1; ++tx)
            for (int ty = y0; ty <= y1; ++ty)
                for (int tz = z0; tz <= z1; ++tz) {
                    const int tl = (tx * NT + ty) * NT + tz;
                    const int p  = lbase[tl] + atomicAdd(&lfill[tl], 1);  // LDS
                    if (p < CAP)
                        lists[(size_t)(type * NTILES + tl) * CAP + p] =
                            (unsigned short)atom;
                }
}

// Phase 2: one block per (segment, tile, type), segment-major so a hot
// tile's segments spread across XCDs. Active segments store 512 partials
// (2KB coalesced) into compact copies[lt][s]; empty segments store nothing.
__global__ __launch_bounds__(256) void gather_seg(
    const float* __restrict__ vC, const float* __restrict__ vN,
    const float* __restrict__ vO, const int* __restrict__ cnt,
    const unsigned short* __restrict__ lists, float* __restrict__ copies,
    int nseg)
{
    const int type = blockIdx.y;
    const float r = type_r(type);
    const float* __restrict__ vecs = (type == 0) ? vC : ((type == 1) ? vN : vO);

    const int s = blockIdx.x / NTILES;        // segment-major
    const int t = blockIdx.x - s * NTILES;
    const int tx = t / (NT * NT);
    const int ty = (t / NT) % NT;
    const int tz = t % NT;

    const int lt  = type * NTILES + t;
    const int n   = min(cnt[lt], CAP);
    const int len = (n + nseg - 1) / nseg;    // 0 when n==0
    const int start = s * len;
    const int end   = min(n, start + len);
    if (start >= end) return;                 // empty segment: no work, no store

    const int tid = threadIdx.x;
    const int lx  = tid >> 6;          // 0..3
    const int ly  = (tid >> 3) & 7;
    const int lz  = tid & 7;

    const float b      = 1.5f * r;
    const float r15sq  = b * b;
    const float rr     = r * r;
    const float E2     = 7.3890562f;
    const float c2a    = 4.0f / (E2 * rr);
    const float c2b    = 12.0f / (E2 * r);
    const float c2c    = 9.0f / E2;
    const float n2orr  = -2.0f / rr;

    const float px0 = 0.5f * (float)(tx * 8 + lx);
    const float px1 = px0 + 2.0f;
    const float py  = 0.5f * (float)(ty * 8 + ly);
    const float pz  = 0.5f * (float)(tz * 8 + lz);

    __shared__ float4 sa[256];
    const unsigned short* __restrict__ lst = lists + (size_t)lt * CAP;

    float acc0 = 0.0f, acc1 = 0.0f;

    for (int base = start; base < end; base += 256) {
        const int m = min(256, end - base);
        if (tid < m) {
            const int idx = (int)lst[base + tid];
            sa[tid] = make_float4(vecs[3 * idx + 0] + 23.5f,
                                  vecs[3 * idx + 1] + 23.5f,
                                  vecs[3 * idx + 2] + 23.5f, 0.0f);
        }
        __syncthreads();

        for (int j = 0; j < m; ++j) {
            const float4 a = sa[j];               // one b128 LDS broadcast
            const float dy  = a.y - py;
            const float dz  = a.z - pz;
            const float syz = fmaf(dy, dy, dz * dz);
            const float dx0 = a.x - px0;
            const float d2a = fmaf(dx0, dx0, syz);
            const float dx1 = a.x - px1;
            const float d2b = fmaf(dx1, dx1, syz);
            const bool h0 = d2a < r15sq;
            const bool h1 = d2b < r15sq;
            if (__ballot(h0 | h1) == 0ull) continue;   // whole-wave miss cull
            if (h0) {
                const float d = sqrtf(d2a);
                acc0 += (d < r) ? __expf(n2orr * d2a)
                                : fmaf(c2a, d2a, fmaf(-c2b, d, c2c));
            }
            if (h1) {
                const float d = sqrtf(d2b);
                acc1 += (d < r) ? __expf(n2orr * d2b)
                                : fmaf(c2a, d2b, fmaf(-c2b, d, c2c));
            }
        }
        __syncthreads();
    }

    float* __restrict__ cp = copies + ((size_t)lt * MAXSEG + s) * 512;
    cp[tid]       = acc0;
    cp[tid + 256] = acc1;
}

// Phase 3: one block per (tile,type). Sums only the segments that stored
// (ss*len < n — exactly gather's store condition), fixed order, writes the
// tile's 512 output cells once (zeros for inactive tiles).
__global__ __launch_bounds__(256) void reduce_kernel(
    const int* __restrict__ cnt, const float* __restrict__ copies,
    float* __restrict__ out, int nseg)
{
    const int type = blockIdx.y;
    const int t = blockIdx.x;
    const int tx = t / (NT * NT);
    const int ty = (t / NT) % NT;
    const int tz = t % NT;
    const int tid = threadIdx.x;
    const int lx  = tid >> 6;
    const int ly  = (tid >> 3) & 7;
    const int lz  = tid & 7;

    const int lt  = type * NTILES + t;
    const int n   = min(cnt[lt], CAP);
    const int len = (n + nseg - 1) / nseg;
    const float* __restrict__ cp = copies + ((size_t)lt * MAXSEG) * 512;

    float o0 = 0.0f, o1 = 0.0f;
    for (int ss = 0; ss < nseg; ++ss) {
        if (ss * len >= n) break;            // segment never stored
        o0 += cp[(size_t)ss * 512 + tid];
        o1 += cp[(size_t)ss * 512 + 256 + tid];
    }

    const int X0 = tx * 8 + lx;
    const int Y  = ty * 8 + ly;
    const int Z  = tz * 8 + lz;
    float* __restrict__ o = out + (size_t)type * NG * NG * NG;
    o[((X0      * NG) + Y) * NG + Z] = o0;
    o[(((X0 + 4) * NG) + Y) * NG + Z] = o1;
}

extern "C" void kernel_launch(void* const* d_in, const int* in_sizes, int n_in,
                              void* d_out, int out_size, void* d_ws, size_t ws_size,
                              hipStream_t stream) {
    const float* vC = (const float*)d_in[0];
    const float* vN = (const float*)d_in[1];
    const float* vO = (const float*)d_in[2];
    float* out = (float*)d_out;

    int* cnt = (int*)d_ws;
    unsigned short* lists = (unsigned short*)((char*)d_ws + LISTS_OFF);
    float* copies = (float*)((char*)d_ws + COPIES_OFF);

    // segments clamped to what the workspace holds (expect 8)
    const size_t copy_bytes = (size_t)3 * NTILES * MAXSEG * 512 * sizeof(float);
    int nseg = (ws_size >= COPIES_OFF + copy_bytes) ? MAXSEG : 4;

    const int natoms = in_sizes[0] / 3;   // 16384

    hipMemsetAsync(cnt, 0, 3 * NTILES * sizeof(int), stream);

    dim3 bgrid((natoms + 255) / 256, 3, 1);
    bin_kernel<<<bgrid, 256, 0, stream>>>(vC, vN, vO, cnt, lists, natoms);

    dim3 ggrid(NTILES * nseg, 3, 1);
    gather_seg<<<ggrid, 256, 0, stream>>>(vC, vN, vO, cnt, lists, copies, nseg);

    dim3 rgrid(NTILES, 3, 1);
    reduce_kernel<<<rgrid, 256, 0, stream>>>(cnt, copies, out, nseg);
}